// Round 1
// baseline (1674.404 us; speedup 1.0000x reference)
//
#include <hip/hip_runtime.h>
#include <math.h>

#define IMG 128
#define CDIM 256
#define NHEADS 8
#define DHEAD 32

// ============================ GEMM: C = scale*(A@B + bias) =================
// A: MxK row-major, B: KxN row-major, bias: N, scale from device ptr (or 1)
#define BM 64
#define BN 64
#define BK 16

__global__ __launch_bounds__(256) void gemm_bias_kernel(
    const float* __restrict__ A, const float* __restrict__ Bm,
    const float* __restrict__ bias, const float* __restrict__ scale_ptr,
    float* __restrict__ Cout, int M, int N, int K)
{
  __shared__ float As[BK][BM];
  __shared__ float Bs[BK][BN];
  const int tid  = threadIdx.x;
  const int row0 = blockIdx.x * BM;
  const int col0 = blockIdx.y * BN;
  const int tm   = (tid >> 4) * 4;     // 0..60
  const int tn   = (tid & 15) * 4;     // 0..60
  const int a_row = tid >> 2;          // 0..63
  const int a_k   = (tid & 3) * 4;     // 0,4,8,12
  const int b_k   = tid >> 4;          // 0..15
  const int b_n   = (tid & 15) * 4;    // 0..60

  float acc[4][4];
#pragma unroll
  for (int i = 0; i < 4; i++)
#pragma unroll
    for (int j = 0; j < 4; j++) acc[i][j] = 0.f;

  for (int k0 = 0; k0 < K; k0 += BK) {
    float4 av = *(const float4*)(A + (size_t)(row0 + a_row) * K + k0 + a_k);
    float4 bv = *(const float4*)(Bm + (size_t)(k0 + b_k) * N + col0 + b_n);
    __syncthreads();
    As[a_k + 0][a_row] = av.x;
    As[a_k + 1][a_row] = av.y;
    As[a_k + 2][a_row] = av.z;
    As[a_k + 3][a_row] = av.w;
    *(float4*)(&Bs[b_k][b_n]) = bv;
    __syncthreads();
#pragma unroll
    for (int kk = 0; kk < BK; kk++) {
      float4 a4 = *(const float4*)(&As[kk][tm]);
      float4 b4 = *(const float4*)(&Bs[kk][tn]);
      acc[0][0] += a4.x * b4.x; acc[0][1] += a4.x * b4.y; acc[0][2] += a4.x * b4.z; acc[0][3] += a4.x * b4.w;
      acc[1][0] += a4.y * b4.x; acc[1][1] += a4.y * b4.y; acc[1][2] += a4.y * b4.z; acc[1][3] += a4.y * b4.w;
      acc[2][0] += a4.z * b4.x; acc[2][1] += a4.z * b4.y; acc[2][2] += a4.z * b4.z; acc[2][3] += a4.z * b4.w;
      acc[3][0] += a4.w * b4.x; acc[3][1] += a4.w * b4.y; acc[3][2] += a4.w * b4.z; acc[3][3] += a4.w * b4.w;
    }
  }
  float s = scale_ptr ? scale_ptr[0] : 1.0f;
  float4 bvv = *(const float4*)(bias + col0 + tn);
#pragma unroll
  for (int i = 0; i < 4; i++) {
    float4 ov;
    ov.x = s * (acc[i][0] + bvv.x);
    ov.y = s * (acc[i][1] + bvv.y);
    ov.z = s * (acc[i][2] + bvv.z);
    ov.w = s * (acc[i][3] + bvv.w);
    *(float4*)(Cout + (size_t)(row0 + tm + i) * N + col0 + tn) = ov;
  }
}

// ============================ grouped 5x5 conv ============================
// kv[b][y][x][oc] = sum_{ky,kx,ic} x[b][y+ky-2][x+kx-2][g*32+ic]*w[ky][kx][ic][g*64+oc'] + bias
// block: 8x8 spatial tile x one group (64 oc) x one batch.
#define PSTR 36   // per-pixel LDS stride (32 ch + 4 pad; keeps 16B align, 2-way conflicts only)

__device__ __forceinline__ void rank1(float a0, float a1, float a2, float a3,
                                      float4 b, float (&acc)[4][4])
{
  acc[0][0] += a0 * b.x; acc[0][1] += a0 * b.y; acc[0][2] += a0 * b.z; acc[0][3] += a0 * b.w;
  acc[1][0] += a1 * b.x; acc[1][1] += a1 * b.y; acc[1][2] += a1 * b.z; acc[1][3] += a1 * b.w;
  acc[2][0] += a2 * b.x; acc[2][1] += a2 * b.y; acc[2][2] += a2 * b.z; acc[2][3] += a2 * b.w;
  acc[3][0] += a3 * b.x; acc[3][1] += a3 * b.y; acc[3][2] += a3 * b.z; acc[3][3] += a3 * b.w;
}

__global__ __launch_bounds__(256) void conv_kv_kernel(
    const float* __restrict__ xin, const float* __restrict__ wgt,
    const float* __restrict__ bias, float* __restrict__ kvout)
{
  __shared__ float patch[144 * PSTR];  // 12x12 pixels x 32 ch (padded)
  __shared__ float wsl[32 * 64];       // one tap: ic x oc
  const int tid = threadIdx.x;
  const int tileIdx = blockIdx.x;      // 0..255
  const int g = blockIdx.y;            // group 0..7
  const int b = blockIdx.z;
  const int ty0 = (tileIdx >> 4) * 8;
  const int tx0 = (tileIdx & 15) * 8;

  // stage input patch (zero-padded)
  for (int idx = tid; idx < 144 * 8; idx += 256) {
    int pix = idx >> 3;
    int c4  = (idx & 7) * 4;
    int py = pix / 12, px = pix % 12;
    int gy = ty0 + py - 2, gx = tx0 + px - 2;
    float4 val = make_float4(0.f, 0.f, 0.f, 0.f);
    if (gy >= 0 && gy < IMG && gx >= 0 && gx < IMG) {
      val = *(const float4*)(xin + ((((size_t)b * IMG + gy) * IMG) + gx) * CDIM + g * 32 + c4);
    }
    float* p = patch + pix * PSTR + c4;
    p[0] = val.x; p[1] = val.y; p[2] = val.z; p[3] = val.w;
  }

  const int a   = tid >> 4;            // 0..15 spatial quad
  const int sy  = a >> 1;              // 0..7
  const int sx0 = (a & 1) * 4;         // 0 or 4
  const int oc0 = (tid & 15) * 4;      // 0..60

  float acc[4][4];
#pragma unroll
  for (int i = 0; i < 4; i++)
#pragma unroll
    for (int j = 0; j < 4; j++) acc[i][j] = 0.f;

  for (int kk = 0; kk < 25; kk++) {
    const int ky = kk / 5, kx = kk % 5;
    __syncthreads();
    for (int idx = tid; idx < 512; idx += 256) {
      int ic = idx >> 4, oc4 = (idx & 15) * 4;
      float4 wv = *(const float4*)(wgt + ((size_t)(kk * 32 + ic)) * 512 + g * 64 + oc4);
      *(float4*)(wsl + ic * 64 + oc4) = wv;
    }
    __syncthreads();
    const float* prow = patch + ((sy + ky) * 12 + (sx0 + kx)) * PSTR;
#pragma unroll
    for (int ic = 0; ic < 32; ic += 4) {
      float4 a0 = *(const float4*)(prow + 0 * PSTR + ic);
      float4 a1 = *(const float4*)(prow + 1 * PSTR + ic);
      float4 a2 = *(const float4*)(prow + 2 * PSTR + ic);
      float4 a3 = *(const float4*)(prow + 3 * PSTR + ic);
      float4 b0 = *(const float4*)(wsl + (ic + 0) * 64 + oc0);
      float4 b1 = *(const float4*)(wsl + (ic + 1) * 64 + oc0);
      float4 b2 = *(const float4*)(wsl + (ic + 2) * 64 + oc0);
      float4 b3 = *(const float4*)(wsl + (ic + 3) * 64 + oc0);
      rank1(a0.x, a1.x, a2.x, a3.x, b0, acc);
      rank1(a0.y, a1.y, a2.y, a3.y, b1, acc);
      rank1(a0.z, a1.z, a2.z, a3.z, b2, acc);
      rank1(a0.w, a1.w, a2.w, a3.w, b3, acc);
    }
  }

  float4 bvv = *(const float4*)(bias + g * 64 + oc0);
  const int oy = ty0 + sy;
#pragma unroll
  for (int i = 0; i < 4; i++) {
    const int ox = tx0 + sx0 + i;
    float4 ov;
    ov.x = acc[i][0] + bvv.x;
    ov.y = acc[i][1] + bvv.y;
    ov.z = acc[i][2] + bvv.z;
    ov.w = acc[i][3] + bvv.w;
    *(float4*)(kvout + ((((size_t)b * IMG + oy) * IMG) + ox) * 512 + g * 64 + oc0) = ov;
  }
}

// ============================ windowed attention ==========================
// one block per (window, head); 128 threads, 2 queries each; online softmax.
// q is read from qo and o is written back in-place (disjoint per block).
__global__ __launch_bounds__(128, 1) void attn_kernel(
    float* __restrict__ qo, const float* __restrict__ kv,
    const float* __restrict__ bias_table)
{
  __shared__ float ksm[128 * 32];
  __shared__ float vsm[128 * 32];
  __shared__ float bsm[961];
  const int tid = threadIdx.x;      // 0..127
  const int n  = blockIdx.x;        // window
  const int hh = blockIdx.y;        // head
  const int b  = n >> 6;
  const int wy = (n >> 3) & 7;
  const int wx = n & 7;
  const int y0 = wy * 16, x0 = wx * 16;

  for (int i = tid; i < 961; i += 128) bsm[i] = bias_table[i * 8 + hh];

  const int t0 = tid, t1 = tid + 128;
  const int qy0 = t0 >> 4, qx0 = t0 & 15;
  const int qy1 = t1 >> 4, qx1 = t1 & 15;
  const int qb0i = (qy0 + 15) * 31 + qx0 + 15;
  const int qb1i = (qy1 + 15) * 31 + qx1 + 15;

  size_t qoff0 = ((((size_t)b * IMG + y0 + qy0) * IMG) + x0 + qx0) * CDIM + hh * 32;
  size_t qoff1 = ((((size_t)b * IMG + y0 + qy1) * IMG) + x0 + qx1) * CDIM + hh * 32;
  float qr0[32], qr1[32];
#pragma unroll
  for (int c4 = 0; c4 < 8; c4++) {
    float4 v0 = *(const float4*)(qo + qoff0 + c4 * 4);
    float4 v1 = *(const float4*)(qo + qoff1 + c4 * 4);
    qr0[c4 * 4 + 0] = v0.x; qr0[c4 * 4 + 1] = v0.y; qr0[c4 * 4 + 2] = v0.z; qr0[c4 * 4 + 3] = v0.w;
    qr1[c4 * 4 + 0] = v1.x; qr1[c4 * 4 + 1] = v1.y; qr1[c4 * 4 + 2] = v1.z; qr1[c4 * 4 + 3] = v1.w;
  }

  float m0 = -1e30f, m1 = -1e30f, l0 = 0.f, l1 = 0.f;
  float o0[32], o1[32];
#pragma unroll
  for (int c = 0; c < 32; c++) { o0[c] = 0.f; o1[c] = 0.f; }
  const float scale = 0.17677669529663687f;  // 1/sqrt(32)

  for (int ch = 0; ch < 2; ch++) {
    __syncthreads();
    {
      int t = ch * 128 + tid;
      int ty = t >> 4, tx = t & 15;
      size_t base = ((((size_t)b * IMG + y0 + ty) * IMG) + x0 + tx) * 512;
      const float4* kp = (const float4*)(kv + base + hh * 32);
      const float4* vp = (const float4*)(kv + base + 256 + hh * 32);
#pragma unroll
      for (int c4 = 0; c4 < 8; c4++) {
        *(float4*)(ksm + tid * 32 + c4 * 4) = kp[c4];
        *(float4*)(vsm + tid * 32 + c4 * 4) = vp[c4];
      }
    }
    __syncthreads();

    for (int kk2 = 0; kk2 < 128; kk2++) {
      const int kt = ch * 128 + kk2;
      const int koff = (kt >> 4) * 31 + (kt & 15);
      const float* kp = ksm + kk2 * 32;
      float s0 = 0.f, s1 = 0.f;
#pragma unroll
      for (int c4 = 0; c4 < 8; c4++) {
        float4 kvv = *(const float4*)(kp + c4 * 4);
        s0 += qr0[c4 * 4 + 0] * kvv.x + qr0[c4 * 4 + 1] * kvv.y + qr0[c4 * 4 + 2] * kvv.z + qr0[c4 * 4 + 3] * kvv.w;
        s1 += qr1[c4 * 4 + 0] * kvv.x + qr1[c4 * 4 + 1] * kvv.y + qr1[c4 * 4 + 2] * kvv.z + qr1[c4 * 4 + 3] * kvv.w;
      }
      s0 = s0 * scale + bsm[qb0i - koff];
      s1 = s1 * scale + bsm[qb1i - koff];
      float nm0 = fmaxf(m0, s0), nm1 = fmaxf(m1, s1);
      float c0 = __expf(m0 - nm0), c1 = __expf(m1 - nm1);
      float p0 = __expf(s0 - nm0), p1 = __expf(s1 - nm1);
      l0 = l0 * c0 + p0; l1 = l1 * c1 + p1;
      m0 = nm0; m1 = nm1;
      const float* vp = vsm + kk2 * 32;
#pragma unroll
      for (int c4 = 0; c4 < 8; c4++) {
        float4 vv = *(const float4*)(vp + c4 * 4);
        o0[c4 * 4 + 0] = o0[c4 * 4 + 0] * c0 + p0 * vv.x;
        o0[c4 * 4 + 1] = o0[c4 * 4 + 1] * c0 + p0 * vv.y;
        o0[c4 * 4 + 2] = o0[c4 * 4 + 2] * c0 + p0 * vv.z;
        o0[c4 * 4 + 3] = o0[c4 * 4 + 3] * c0 + p0 * vv.w;
        o1[c4 * 4 + 0] = o1[c4 * 4 + 0] * c1 + p1 * vv.x;
        o1[c4 * 4 + 1] = o1[c4 * 4 + 1] * c1 + p1 * vv.y;
        o1[c4 * 4 + 2] = o1[c4 * 4 + 2] * c1 + p1 * vv.z;
        o1[c4 * 4 + 3] = o1[c4 * 4 + 3] * c1 + p1 * vv.w;
      }
    }
  }

  const float inv0 = 1.0f / l0;
  const float inv1 = 1.0f / l1;
#pragma unroll
  for (int c4 = 0; c4 < 8; c4++) {
    float4 ov0, ov1;
    ov0.x = o0[c4 * 4 + 0] * inv0; ov0.y = o0[c4 * 4 + 1] * inv0;
    ov0.z = o0[c4 * 4 + 2] * inv0; ov0.w = o0[c4 * 4 + 3] * inv0;
    ov1.x = o1[c4 * 4 + 0] * inv1; ov1.y = o1[c4 * 4 + 1] * inv1;
    ov1.z = o1[c4 * 4 + 2] * inv1; ov1.w = o1[c4 * 4 + 3] * inv1;
    *(float4*)(qo + qoff0 + c4 * 4) = ov0;
    *(float4*)(qo + qoff1 + c4 * 4) = ov1;
  }
}

// ============================ launch ======================================
extern "C" void kernel_launch(void* const* d_in, const int* in_sizes, int n_in,
                              void* d_out, int out_size, void* d_ws, size_t ws_size,
                              hipStream_t stream) {
  const float* x_wsa      = (const float*)d_in[0];
  const float* x_orig     = (const float*)d_in[1];
  const float* q_w        = (const float*)d_in[2];
  const float* q_b        = (const float*)d_in[3];
  const float* kv_w       = (const float*)d_in[4];
  const float* kv_b       = (const float*)d_in[5];
  const float* out_w      = (const float*)d_in[6];
  const float* out_b      = (const float*)d_in[7];
  const float* bias_table = (const float*)d_in[8];
  const float* rezero     = (const float*)d_in[9];
  float* out = (float*)d_out;

  float* qo    = (float*)d_ws;                          // 4*128*128*256 f32 = 64 MB (q, then o in-place)
  float* kvbuf = (float*)((char*)d_ws + 67108864);      // 4*128*128*512 f32 = 128 MB

  const int M = 4 * IMG * IMG;  // 65536

  gemm_bias_kernel<<<dim3(M / BM, CDIM / BN), 256, 0, stream>>>(
      x_wsa, q_w, q_b, nullptr, qo, M, CDIM, CDIM);

  conv_kv_kernel<<<dim3(256, 8, 4), 256, 0, stream>>>(x_orig, kv_w, kv_b, kvbuf);

  attn_kernel<<<dim3(256, 8), 128, 0, stream>>>(qo, kvbuf, bias_table);

  gemm_bias_kernel<<<dim3(M / BM, CDIM / BN), 256, 0, stream>>>(
      qo, out_w, out_b, rezero, out, M, CDIM, CDIM);
}

// Round 2
// 1106.150 us; speedup vs baseline: 1.5137x; 1.5137x over previous
//
#include <hip/hip_runtime.h>
#include <math.h>

#define IMG 128
#define CDIM 256
#define NHEADS 8
#define DHEAD 32

typedef _Float16 half8 __attribute__((ext_vector_type(8)));
typedef _Float16 half4 __attribute__((ext_vector_type(4)));
typedef float floatx4 __attribute__((ext_vector_type(4)));

// ============================ GEMM: C = scale*(A@B + bias) =================
#define BM 64
#define BN 64
#define BK 16

__global__ __launch_bounds__(256) void gemm_bias_kernel(
    const float* __restrict__ A, const float* __restrict__ Bm,
    const float* __restrict__ bias, const float* __restrict__ scale_ptr,
    float* __restrict__ Cout, int M, int N, int K)
{
  __shared__ float As[BK][BM];
  __shared__ float Bs[BK][BN];
  const int tid  = threadIdx.x;
  const int row0 = blockIdx.x * BM;
  const int col0 = blockIdx.y * BN;
  const int tm   = (tid >> 4) * 4;
  const int tn   = (tid & 15) * 4;
  const int a_row = tid >> 2;
  const int a_k   = (tid & 3) * 4;
  const int b_k   = tid >> 4;
  const int b_n   = (tid & 15) * 4;

  float acc[4][4];
#pragma unroll
  for (int i = 0; i < 4; i++)
#pragma unroll
    for (int j = 0; j < 4; j++) acc[i][j] = 0.f;

  for (int k0 = 0; k0 < K; k0 += BK) {
    float4 av = *(const float4*)(A + (size_t)(row0 + a_row) * K + k0 + a_k);
    float4 bv = *(const float4*)(Bm + (size_t)(k0 + b_k) * N + col0 + b_n);
    __syncthreads();
    As[a_k + 0][a_row] = av.x;
    As[a_k + 1][a_row] = av.y;
    As[a_k + 2][a_row] = av.z;
    As[a_k + 3][a_row] = av.w;
    *(float4*)(&Bs[b_k][b_n]) = bv;
    __syncthreads();
#pragma unroll
    for (int kk = 0; kk < BK; kk++) {
      float4 a4 = *(const float4*)(&As[kk][tm]);
      float4 b4 = *(const float4*)(&Bs[kk][tn]);
      acc[0][0] += a4.x * b4.x; acc[0][1] += a4.x * b4.y; acc[0][2] += a4.x * b4.z; acc[0][3] += a4.x * b4.w;
      acc[1][0] += a4.y * b4.x; acc[1][1] += a4.y * b4.y; acc[1][2] += a4.y * b4.z; acc[1][3] += a4.y * b4.w;
      acc[2][0] += a4.z * b4.x; acc[2][1] += a4.z * b4.y; acc[2][2] += a4.z * b4.z; acc[2][3] += a4.z * b4.w;
      acc[3][0] += a4.w * b4.x; acc[3][1] += a4.w * b4.y; acc[3][2] += a4.w * b4.z; acc[3][3] += a4.w * b4.w;
    }
  }
  float s = scale_ptr ? scale_ptr[0] : 1.0f;
  float4 bvv = *(const float4*)(bias + col0 + tn);
#pragma unroll
  for (int i = 0; i < 4; i++) {
    float4 ov;
    ov.x = s * (acc[i][0] + bvv.x);
    ov.y = s * (acc[i][1] + bvv.y);
    ov.z = s * (acc[i][2] + bvv.z);
    ov.w = s * (acc[i][3] + bvv.w);
    *(float4*)(Cout + (size_t)(row0 + tm + i) * N + col0 + tn) = ov;
  }
}

// ============================ grouped 5x5 conv ============================
#define PSTR 36

__device__ __forceinline__ void rank1(float a0, float a1, float a2, float a3,
                                      float4 b, float (&acc)[4][4])
{
  acc[0][0] += a0 * b.x; acc[0][1] += a0 * b.y; acc[0][2] += a0 * b.z; acc[0][3] += a0 * b.w;
  acc[1][0] += a1 * b.x; acc[1][1] += a1 * b.y; acc[1][2] += a1 * b.z; acc[1][3] += a1 * b.w;
  acc[2][0] += a2 * b.x; acc[2][1] += a2 * b.y; acc[2][2] += a2 * b.z; acc[2][3] += a2 * b.w;
  acc[3][0] += a3 * b.x; acc[3][1] += a3 * b.y; acc[3][2] += a3 * b.z; acc[3][3] += a3 * b.w;
}

__global__ __launch_bounds__(256) void conv_kv_kernel(
    const float* __restrict__ xin, const float* __restrict__ wgt,
    const float* __restrict__ bias, float* __restrict__ kvout)
{
  __shared__ float patch[144 * PSTR];
  __shared__ float wsl[32 * 64];
  const int tid = threadIdx.x;
  const int tileIdx = blockIdx.x;
  const int g = blockIdx.y;
  const int b = blockIdx.z;
  const int ty0 = (tileIdx >> 4) * 8;
  const int tx0 = (tileIdx & 15) * 8;

  for (int idx = tid; idx < 144 * 8; idx += 256) {
    int pix = idx >> 3;
    int c4  = (idx & 7) * 4;
    int py = pix / 12, px = pix % 12;
    int gy = ty0 + py - 2, gx = tx0 + px - 2;
    float4 val = make_float4(0.f, 0.f, 0.f, 0.f);
    if (gy >= 0 && gy < IMG && gx >= 0 && gx < IMG) {
      val = *(const float4*)(xin + ((((size_t)b * IMG + gy) * IMG) + gx) * CDIM + g * 32 + c4);
    }
    float* p = patch + pix * PSTR + c4;
    p[0] = val.x; p[1] = val.y; p[2] = val.z; p[3] = val.w;
  }

  const int a   = tid >> 4;
  const int sy  = a >> 1;
  const int sx0 = (a & 1) * 4;
  const int oc0 = (tid & 15) * 4;

  float acc[4][4];
#pragma unroll
  for (int i = 0; i < 4; i++)
#pragma unroll
    for (int j = 0; j < 4; j++) acc[i][j] = 0.f;

  for (int kk = 0; kk < 25; kk++) {
    const int ky = kk / 5, kx = kk % 5;
    __syncthreads();
    for (int idx = tid; idx < 512; idx += 256) {
      int ic = idx >> 4, oc4 = (idx & 15) * 4;
      float4 wv = *(const float4*)(wgt + ((size_t)(kk * 32 + ic)) * 512 + g * 64 + oc4);
      *(float4*)(wsl + ic * 64 + oc4) = wv;
    }
    __syncthreads();
    const float* prow = patch + ((sy + ky) * 12 + (sx0 + kx)) * PSTR;
#pragma unroll
    for (int ic = 0; ic < 32; ic += 4) {
      float4 a0 = *(const float4*)(prow + 0 * PSTR + ic);
      float4 a1 = *(const float4*)(prow + 1 * PSTR + ic);
      float4 a2 = *(const float4*)(prow + 2 * PSTR + ic);
      float4 a3 = *(const float4*)(prow + 3 * PSTR + ic);
      float4 b0 = *(const float4*)(wsl + (ic + 0) * 64 + oc0);
      float4 b1 = *(const float4*)(wsl + (ic + 1) * 64 + oc0);
      float4 b2 = *(const float4*)(wsl + (ic + 2) * 64 + oc0);
      float4 b3 = *(const float4*)(wsl + (ic + 3) * 64 + oc0);
      rank1(a0.x, a1.x, a2.x, a3.x, b0, acc);
      rank1(a0.y, a1.y, a2.y, a3.y, b1, acc);
      rank1(a0.z, a1.z, a2.z, a3.z, b2, acc);
      rank1(a0.w, a1.w, a2.w, a3.w, b3, acc);
    }
  }

  float4 bvv = *(const float4*)(bias + g * 64 + oc0);
  const int oy = ty0 + sy;
#pragma unroll
  for (int i = 0; i < 4; i++) {
    const int ox = tx0 + sx0 + i;
    float4 ov;
    ov.x = acc[i][0] + bvv.x;
    ov.y = acc[i][1] + bvv.y;
    ov.z = acc[i][2] + bvv.z;
    ov.w = acc[i][3] + bvv.w;
    *(float4*)(kvout + ((((size_t)b * IMG + oy) * IMG) + ox) * 512 + g * 64 + oc0) = ov;
  }
}

// ====================== MFMA flash attention (S^T trick) ===================
// One block per (window, head), 256 thr = 4 waves, 64 queries/wave.
// S^T = K·Q^T via 16x16x32 f16 MFMA; softmax over columns of S^T (in-lane +
// shfl ^16 ^32); P^T in C-layout IS the B-frag of 16x16x16 f16 MFMA, so
// O^T = V^T·P^T needs no data movement for P. Only V is transposed in LDS.
#define KSTR 40    // K row stride in f16 (32 data + 8 pad)
#define VSTR 264   // Vt row stride in f16 (256 tokens + 8 pad)

__global__ __launch_bounds__(256, 3) void attn_mfma_kernel(
    float* __restrict__ qo, const float* __restrict__ kv,
    const float* __restrict__ bias_table)
{
  __shared__ _Float16 Kl[256 * KSTR];   // 20480 B
  __shared__ _Float16 Vt[32 * VSTR];    // 16896 B
  __shared__ float bsm[961];            //  3844 B

  const int tid = threadIdx.x;
  const int n  = blockIdx.x;
  const int hh = blockIdx.y;
  const int b  = n >> 6;
  const int wy = (n >> 3) & 7;
  const int wx = n & 7;
  const int y0 = wy * 16, x0 = wx * 16;

  for (int i = tid; i < 961; i += 256) bsm[i] = bias_table[i * 8 + hh];

  // ---- stage K (row-major f16) and V (transposed f16) ----
  {
    const int ty = tid >> 4, tx = tid & 15;
    size_t base = ((((size_t)b * IMG + y0 + ty) * IMG) + x0 + tx) * 512;
    const float4* kp = (const float4*)(kv + base + hh * 32);
    const float4* vp = (const float4*)(kv + base + 256 + hh * 32);
    _Float16 kh[32];
#pragma unroll
    for (int c4 = 0; c4 < 8; c4++) {
      float4 v = kp[c4];
      kh[c4 * 4 + 0] = (_Float16)v.x; kh[c4 * 4 + 1] = (_Float16)v.y;
      kh[c4 * 4 + 2] = (_Float16)v.z; kh[c4 * 4 + 3] = (_Float16)v.w;
    }
#pragma unroll
    for (int i = 0; i < 4; i++)
      *(half8*)(Kl + tid * KSTR + i * 8) = *(half8*)(kh + i * 8);
#pragma unroll
    for (int c4 = 0; c4 < 8; c4++) {
      float4 v = vp[c4];
      Vt[(c4 * 4 + 0) * VSTR + tid] = (_Float16)v.x;
      Vt[(c4 * 4 + 1) * VSTR + tid] = (_Float16)v.y;
      Vt[(c4 * 4 + 2) * VSTR + tid] = (_Float16)v.z;
      Vt[(c4 * 4 + 3) * VSTR + tid] = (_Float16)v.w;
    }
  }

  const int wave = tid >> 6, lane = tid & 63;
  const int lq = lane & 15, quad = lane >> 4;

  // ---- persistent Q B-frags (4 q-tiles of 16 queries) ----
  half8 qB[4];
  int qtok[4], qbase[4];
  size_t qptr[4];
#pragma unroll
  for (int qt = 0; qt < 4; qt++) {
    int tok = wave * 64 + qt * 16 + lq;
    qtok[qt] = tok;
    int qy = tok >> 4, qx = tok & 15;
    qbase[qt] = (qy + 15) * 31 + (qx + 15);
    size_t p = ((((size_t)b * IMG + y0 + qy) * IMG) + x0 + qx) * CDIM + hh * 32;
    qptr[qt] = p;
    float4 a = *(const float4*)(qo + p + quad * 8);
    float4 c = *(const float4*)(qo + p + quad * 8 + 4);
    half8 q8;
    q8[0] = (_Float16)a.x; q8[1] = (_Float16)a.y; q8[2] = (_Float16)a.z; q8[3] = (_Float16)a.w;
    q8[4] = (_Float16)c.x; q8[5] = (_Float16)c.y; q8[6] = (_Float16)c.z; q8[7] = (_Float16)c.w;
    qB[qt] = q8;
  }

  __syncthreads();

  float m[4] = {-1e30f, -1e30f, -1e30f, -1e30f};
  float l[4] = {0.f, 0.f, 0.f, 0.f};
  floatx4 Ot[2][4];
#pragma unroll
  for (int dt = 0; dt < 2; dt++)
#pragma unroll
    for (int qt = 0; qt < 4; qt++) Ot[dt][qt] = (floatx4){0.f, 0.f, 0.f, 0.f};

  const float scale = 0.17677669529663687f;  // 1/sqrt(32)

  for (int ch = 0; ch < 8; ch++) {
    // K A-frags for this chunk's two key-tiles
    half8 kA[2];
#pragma unroll
    for (int kt = 0; kt < 2; kt++)
      kA[kt] = *(const half8*)(Kl + (ch * 32 + kt * 16 + lq) * KSTR + quad * 8);

    // S^T = K · Q^T
    floatx4 S[4][2];
#pragma unroll
    for (int qt = 0; qt < 4; qt++)
#pragma unroll
      for (int kt = 0; kt < 2; kt++)
        S[qt][kt] = __builtin_amdgcn_mfma_f32_16x16x32_f16(
            kA[kt], qB[qt], (floatx4){0.f, 0.f, 0.f, 0.f}, 0, 0, 0);

    // V^T A-frags
    half4 vA[2][2];
#pragma unroll
    for (int dt = 0; dt < 2; dt++)
#pragma unroll
      for (int kt = 0; kt < 2; kt++)
        vA[dt][kt] = *(const half4*)(Vt + (dt * 16 + lq) * VSTR +
                                     ch * 32 + kt * 16 + quad * 4);

    // bias + scale + online softmax, per q-tile
    half4 pB[4][2];
#pragma unroll
    for (int qt = 0; qt < 4; qt++) {
      float sv[8];
#pragma unroll
      for (int kt = 0; kt < 2; kt++) {
        int keybase = ch * 32 + kt * 16 + quad * 4;
        int koff = (keybase >> 4) * 31 + (keybase & 15);
#pragma unroll
        for (int r = 0; r < 4; r++)
          sv[kt * 4 + r] = S[qt][kt][r] * scale + bsm[qbase[qt] - koff - r];
      }
      float mx = sv[0];
#pragma unroll
      for (int i = 1; i < 8; i++) mx = fmaxf(mx, sv[i]);
      mx = fmaxf(mx, __shfl_xor(mx, 16));
      mx = fmaxf(mx, __shfl_xor(mx, 32));
      float mn = fmaxf(m[qt], mx);
      float c = __expf(m[qt] - mn);
      m[qt] = mn;
      float ps = 0.f;
#pragma unroll
      for (int i = 0; i < 8; i++) { sv[i] = __expf(sv[i] - mn); ps += sv[i]; }
      ps += __shfl_xor(ps, 16);
      ps += __shfl_xor(ps, 32);
      l[qt] = l[qt] * c + ps;
#pragma unroll
      for (int dt = 0; dt < 2; dt++) {
        Ot[dt][qt][0] *= c; Ot[dt][qt][1] *= c;
        Ot[dt][qt][2] *= c; Ot[dt][qt][3] *= c;
      }
#pragma unroll
      for (int kt = 0; kt < 2; kt++) {
        half4 p4;
        p4[0] = (_Float16)sv[kt * 4 + 0]; p4[1] = (_Float16)sv[kt * 4 + 1];
        p4[2] = (_Float16)sv[kt * 4 + 2]; p4[3] = (_Float16)sv[kt * 4 + 3];
        pB[qt][kt] = p4;
      }
    }

    // O^T += V^T · P^T
#pragma unroll
    for (int qt = 0; qt < 4; qt++)
#pragma unroll
      for (int dt = 0; dt < 2; dt++)
#pragma unroll
        for (int kt = 0; kt < 2; kt++)
          Ot[dt][qt] = __builtin_amdgcn_mfma_f32_16x16x16f16(
              vA[dt][kt], pB[qt][kt], Ot[dt][qt], 0, 0, 0);
  }

  // ---- epilogue: scale by 1/l, write O back in place of Q ----
#pragma unroll
  for (int qt = 0; qt < 4; qt++) {
    float inv = 1.0f / l[qt];
#pragma unroll
    for (int dt = 0; dt < 2; dt++) {
      float4 ov;
      ov.x = Ot[dt][qt][0] * inv;
      ov.y = Ot[dt][qt][1] * inv;
      ov.z = Ot[dt][qt][2] * inv;
      ov.w = Ot[dt][qt][3] * inv;
      *(float4*)(qo + qptr[qt] + dt * 16 + quad * 4) = ov;
    }
  }
}

// ============================ launch ======================================
extern "C" void kernel_launch(void* const* d_in, const int* in_sizes, int n_in,
                              void* d_out, int out_size, void* d_ws, size_t ws_size,
                              hipStream_t stream) {
  const float* x_wsa      = (const float*)d_in[0];
  const float* x_orig     = (const float*)d_in[1];
  const float* q_w        = (const float*)d_in[2];
  const float* q_b        = (const float*)d_in[3];
  const float* kv_w       = (const float*)d_in[4];
  const float* kv_b       = (const float*)d_in[5];
  const float* out_w      = (const float*)d_in[6];
  const float* out_b      = (const float*)d_in[7];
  const float* bias_table = (const float*)d_in[8];
  const float* rezero     = (const float*)d_in[9];
  float* out = (float*)d_out;

  float* qo    = (float*)d_ws;                          // 64 MB (q, then o in-place)
  float* kvbuf = (float*)((char*)d_ws + 67108864);      // 128 MB

  const int M = 4 * IMG * IMG;  // 65536

  gemm_bias_kernel<<<dim3(M / BM, CDIM / BN), 256, 0, stream>>>(
      x_wsa, q_w, q_b, nullptr, qo, M, CDIM, CDIM);

  conv_kv_kernel<<<dim3(256, 8, 4), 256, 0, stream>>>(x_orig, kv_w, kv_b, kvbuf);

  attn_mfma_kernel<<<dim3(256, 8), 256, 0, stream>>>(qo, kvbuf, bias_table);

  gemm_bias_kernel<<<dim3(M / BM, CDIM / BN), 256, 0, stream>>>(
      qo, out_w, out_b, rezero, out, M, CDIM, CDIM);
}

// Round 3
// 503.985 us; speedup vs baseline: 3.3223x; 2.1948x over previous
//
#include <hip/hip_runtime.h>
#include <math.h>

#define IMG 128
#define CDIM 256
#define NHEADS 8
#define DHEAD 32

typedef _Float16 half8 __attribute__((ext_vector_type(8)));
typedef _Float16 half4 __attribute__((ext_vector_type(4)));
typedef float floatx4 __attribute__((ext_vector_type(4)));

// ============================ GEMM: C = scale*(A@B + bias) =================
#define BM 64
#define BN 64
#define BK 16

__global__ __launch_bounds__(256) void gemm_bias_kernel(
    const float* __restrict__ A, const float* __restrict__ Bm,
    const float* __restrict__ bias, const float* __restrict__ scale_ptr,
    float* __restrict__ Cout, int M, int N, int K)
{
  __shared__ float As[BK][BM];
  __shared__ float Bs[BK][BN];
  const int tid  = threadIdx.x;
  const int row0 = blockIdx.x * BM;
  const int col0 = blockIdx.y * BN;
  const int tm   = (tid >> 4) * 4;
  const int tn   = (tid & 15) * 4;
  const int a_row = tid >> 2;
  const int a_k   = (tid & 3) * 4;
  const int b_k   = tid >> 4;
  const int b_n   = (tid & 15) * 4;

  float acc[4][4];
#pragma unroll
  for (int i = 0; i < 4; i++)
#pragma unroll
    for (int j = 0; j < 4; j++) acc[i][j] = 0.f;

  for (int k0 = 0; k0 < K; k0 += BK) {
    float4 av = *(const float4*)(A + (size_t)(row0 + a_row) * K + k0 + a_k);
    float4 bv = *(const float4*)(Bm + (size_t)(k0 + b_k) * N + col0 + b_n);
    __syncthreads();
    As[a_k + 0][a_row] = av.x;
    As[a_k + 1][a_row] = av.y;
    As[a_k + 2][a_row] = av.z;
    As[a_k + 3][a_row] = av.w;
    *(float4*)(&Bs[b_k][b_n]) = bv;
    __syncthreads();
#pragma unroll
    for (int kk = 0; kk < BK; kk++) {
      float4 a4 = *(const float4*)(&As[kk][tm]);
      float4 b4 = *(const float4*)(&Bs[kk][tn]);
      acc[0][0] += a4.x * b4.x; acc[0][1] += a4.x * b4.y; acc[0][2] += a4.x * b4.z; acc[0][3] += a4.x * b4.w;
      acc[1][0] += a4.y * b4.x; acc[1][1] += a4.y * b4.y; acc[1][2] += a4.y * b4.z; acc[1][3] += a4.y * b4.w;
      acc[2][0] += a4.z * b4.x; acc[2][1] += a4.z * b4.y; acc[2][2] += a4.z * b4.z; acc[2][3] += a4.z * b4.w;
      acc[3][0] += a4.w * b4.x; acc[3][1] += a4.w * b4.y; acc[3][2] += a4.w * b4.z; acc[3][3] += a4.w * b4.w;
    }
  }
  float s = scale_ptr ? scale_ptr[0] : 1.0f;
  float4 bvv = *(const float4*)(bias + col0 + tn);
#pragma unroll
  for (int i = 0; i < 4; i++) {
    float4 ov;
    ov.x = s * (acc[i][0] + bvv.x);
    ov.y = s * (acc[i][1] + bvv.y);
    ov.z = s * (acc[i][2] + bvv.z);
    ov.w = s * (acc[i][3] + bvv.w);
    *(float4*)(Cout + (size_t)(row0 + tm + i) * N + col0 + tn) = ov;
  }
}

// ==================== weight pre-transpose: w -> wT f16 ====================
// w: (25*32, 512) f32, element ((tap*32+ic)*512 + g*64+oc)
// wT: (8, 25, 64, 32) f16, element (((g*25+tap)*64+oc)*32 + ic)
__global__ __launch_bounds__(512) void wt_kernel(const float* __restrict__ w,
                                                 _Float16* __restrict__ wT)
{
  const int tap = blockIdx.x;          // 0..24
  const int t = threadIdx.x;           // 0..511 = global oc
  const int g = t >> 6, o = t & 63;
  _Float16 h[32];
#pragma unroll
  for (int ic = 0; ic < 32; ic++)
    h[ic] = (_Float16)w[(size_t)(tap * 32 + ic) * 512 + t];
  half8* dst = (half8*)(wT + (((size_t)g * 25 + tap) * 64 + o) * 32);
#pragma unroll
  for (int i = 0; i < 4; i++) dst[i] = *(half8*)(h + i * 8);
}

// ==================== grouped 5x5 conv via implicit-GEMM MFMA ==============
// One block: 16x16 pixel tile x group x batch. A=weights[oc][ic] (M=oc),
// B=activations[ic][pixel] (N=px row), K=ic per tap; 25 taps accumulated.
// Output D[m=oc=quad*4+reg][n=px=lane&15] -> half4 store per (mt,nt).
#define PS 40   // patch pixel stride in f16 (32 ch + 8 pad; 16B-aligned rows)
#define PW 20

__global__ __launch_bounds__(256, 2) void conv_mfma_kernel(
    const float* __restrict__ xin, const _Float16* __restrict__ wT,
    const float* __restrict__ bias, _Float16* __restrict__ kvout)
{
  __shared__ _Float16 patch[400 * PS];    // 32000 B
  __shared__ _Float16 wsl[5 * 64 * 32];   // 20480 B (5 taps of one ky row)

  const int tid  = threadIdx.x;
  const int tile = blockIdx.x;            // 0..63
  const int g    = blockIdx.y;
  const int b    = blockIdx.z;
  const int ty0 = (tile >> 3) * 16, tx0 = (tile & 7) * 16;

  // ---- stage 20x20x32 input patch as f16 (zero-padded halo) ----
  for (int idx = tid; idx < 800; idx += 256) {
    int pix = idx >> 1, c0 = (idx & 1) * 16;
    int py = pix / 20, px = pix - py * 20;
    int gy = ty0 + py - 2, gx = tx0 + px - 2;
    _Float16 h[16];
    if ((unsigned)gy < (unsigned)IMG && (unsigned)gx < (unsigned)IMG) {
      const float4* src = (const float4*)(xin + ((((size_t)b * IMG + gy) * IMG) + gx) * CDIM + g * 32 + c0);
#pragma unroll
      for (int i = 0; i < 4; i++) {
        float4 v = src[i];
        h[i * 4 + 0] = (_Float16)v.x; h[i * 4 + 1] = (_Float16)v.y;
        h[i * 4 + 2] = (_Float16)v.z; h[i * 4 + 3] = (_Float16)v.w;
      }
    } else {
#pragma unroll
      for (int i = 0; i < 16; i++) h[i] = (_Float16)0.f;
    }
    *(half8*)(patch + pix * PS + c0)     = *(half8*)h;
    *(half8*)(patch + pix * PS + c0 + 8) = *(half8*)(h + 8);
  }

  const int wave = tid >> 6, lane = tid & 63;
  const int lq = lane & 15, quad = lane >> 4;

  floatx4 acc[4][4];  // [mt = oc-tile][nt = pixel-row]
#pragma unroll
  for (int i = 0; i < 4; i++)
#pragma unroll
    for (int j = 0; j < 4; j++) acc[i][j] = (floatx4){0.f, 0.f, 0.f, 0.f};

  const _Float16* wg = wT + (size_t)g * 25 * 64 * 32;

  for (int ky = 0; ky < 5; ky++) {
    __syncthreads();
    {
      const half8* src = (const half8*)(wg + (size_t)ky * 5 * 64 * 32);
      half8* dst = (half8*)wsl;
      for (int i = tid; i < 1280; i += 256) dst[i] = src[i];
    }
    __syncthreads();
#pragma unroll
    for (int kx = 0; kx < 5; kx++) {
      half8 bfr[4];
#pragma unroll
      for (int nt = 0; nt < 4; nt++) {
        int py = wave * 4 + nt + ky;
        bfr[nt] = *(const half8*)(patch + (py * PW + lq + kx) * PS + quad * 8);
      }
#pragma unroll
      for (int mt = 0; mt < 4; mt++) {
        half8 afr = *(const half8*)(wsl + ((kx * 64) + mt * 16 + lq) * 32 + quad * 8);
#pragma unroll
        for (int nt = 0; nt < 4; nt++)
          acc[mt][nt] = __builtin_amdgcn_mfma_f32_16x16x32_f16(afr, bfr[nt], acc[mt][nt], 0, 0, 0);
      }
    }
  }

  // ---- epilogue: add bias, store f16 ----
#pragma unroll
  for (int mt = 0; mt < 4; mt++) {
    float4 bv = *(const float4*)(bias + g * 64 + mt * 16 + quad * 4);
#pragma unroll
    for (int nt = 0; nt < 4; nt++) {
      int oy = ty0 + wave * 4 + nt;
      int ox = tx0 + lq;
      half4 ov;
      ov[0] = (_Float16)(acc[mt][nt][0] + bv.x);
      ov[1] = (_Float16)(acc[mt][nt][1] + bv.y);
      ov[2] = (_Float16)(acc[mt][nt][2] + bv.z);
      ov[3] = (_Float16)(acc[mt][nt][3] + bv.w);
      *(half4*)(kvout + ((((size_t)b * IMG + oy) * IMG) + ox) * 512 + g * 64 + mt * 16 + quad * 4) = ov;
    }
  }
}

// ====================== MFMA flash attention (S^T trick) ===================
#define KSTR 40    // K row stride in f16 (32 data + 8 pad)
#define VSTR 264   // Vt row stride in f16 (256 tokens + 8 pad)

__global__ __launch_bounds__(256, 3) void attn_mfma_kernel(
    float* __restrict__ qo, const _Float16* __restrict__ kv,
    const float* __restrict__ bias_table)
{
  __shared__ _Float16 Kl[256 * KSTR];
  __shared__ _Float16 Vt[32 * VSTR];
  __shared__ float bsm[961];

  const int tid = threadIdx.x;
  const int n  = blockIdx.x;
  const int hh = blockIdx.y;
  const int b  = n >> 6;
  const int wy = (n >> 3) & 7;
  const int wx = n & 7;
  const int y0 = wy * 16, x0 = wx * 16;

  for (int i = tid; i < 961; i += 256) bsm[i] = bias_table[i * 8 + hh];

  // ---- stage K (row-major f16) and V (transposed f16) ----
  {
    const int ty = tid >> 4, tx = tid & 15;
    size_t base = ((((size_t)b * IMG + y0 + ty) * IMG) + x0 + tx) * 512;
    const half8* kp = (const half8*)(kv + base + hh * 32);
    const half8* vp = (const half8*)(kv + base + 256 + hh * 32);
#pragma unroll
    for (int i = 0; i < 4; i++)
      *(half8*)(Kl + tid * KSTR + i * 8) = kp[i];
    half8 vh[4];
#pragma unroll
    for (int i = 0; i < 4; i++) vh[i] = vp[i];
#pragma unroll
    for (int i = 0; i < 4; i++)
#pragma unroll
      for (int j = 0; j < 8; j++)
        Vt[(i * 8 + j) * VSTR + tid] = vh[i][j];
  }

  const int wave = tid >> 6, lane = tid & 63;
  const int lq = lane & 15, quad = lane >> 4;

  half8 qB[4];
  int qbase[4];
  size_t qptr[4];
#pragma unroll
  for (int qt = 0; qt < 4; qt++) {
    int tok = wave * 64 + qt * 16 + lq;
    int qy = tok >> 4, qx = tok & 15;
    qbase[qt] = (qy + 15) * 31 + (qx + 15);
    size_t p = ((((size_t)b * IMG + y0 + qy) * IMG) + x0 + qx) * CDIM + hh * 32;
    qptr[qt] = p;
    float4 a = *(const float4*)(qo + p + quad * 8);
    float4 c = *(const float4*)(qo + p + quad * 8 + 4);
    half8 q8;
    q8[0] = (_Float16)a.x; q8[1] = (_Float16)a.y; q8[2] = (_Float16)a.z; q8[3] = (_Float16)a.w;
    q8[4] = (_Float16)c.x; q8[5] = (_Float16)c.y; q8[6] = (_Float16)c.z; q8[7] = (_Float16)c.w;
    qB[qt] = q8;
  }

  __syncthreads();

  float m[4] = {-1e30f, -1e30f, -1e30f, -1e30f};
  float l[4] = {0.f, 0.f, 0.f, 0.f};
  floatx4 Ot[2][4];
#pragma unroll
  for (int dt = 0; dt < 2; dt++)
#pragma unroll
    for (int qt = 0; qt < 4; qt++) Ot[dt][qt] = (floatx4){0.f, 0.f, 0.f, 0.f};

  const float scale = 0.17677669529663687f;

  for (int ch = 0; ch < 8; ch++) {
    half8 kA[2];
#pragma unroll
    for (int kt = 0; kt < 2; kt++)
      kA[kt] = *(const half8*)(Kl + (ch * 32 + kt * 16 + lq) * KSTR + quad * 8);

    floatx4 S[4][2];
#pragma unroll
    for (int qt = 0; qt < 4; qt++)
#pragma unroll
      for (int kt = 0; kt < 2; kt++)
        S[qt][kt] = __builtin_amdgcn_mfma_f32_16x16x32_f16(
            kA[kt], qB[qt], (floatx4){0.f, 0.f, 0.f, 0.f}, 0, 0, 0);

    half4 vA[2][2];
#pragma unroll
    for (int dt = 0; dt < 2; dt++)
#pragma unroll
      for (int kt = 0; kt < 2; kt++)
        vA[dt][kt] = *(const half4*)(Vt + (dt * 16 + lq) * VSTR +
                                     ch * 32 + kt * 16 + quad * 4);

    half4 pB[4][2];
#pragma unroll
    for (int qt = 0; qt < 4; qt++) {
      float sv[8];
#pragma unroll
      for (int kt = 0; kt < 2; kt++) {
        int keybase = ch * 32 + kt * 16 + quad * 4;
        int koff = (keybase >> 4) * 31 + (keybase & 15);
#pragma unroll
        for (int r = 0; r < 4; r++)
          sv[kt * 4 + r] = S[qt][kt][r] * scale + bsm[qbase[qt] - koff - r];
      }
      float mx = sv[0];
#pragma unroll
      for (int i = 1; i < 8; i++) mx = fmaxf(mx, sv[i]);
      mx = fmaxf(mx, __shfl_xor(mx, 16));
      mx = fmaxf(mx, __shfl_xor(mx, 32));
      float mn = fmaxf(m[qt], mx);
      float c = __expf(m[qt] - mn);
      m[qt] = mn;
      float ps = 0.f;
#pragma unroll
      for (int i = 0; i < 8; i++) { sv[i] = __expf(sv[i] - mn); ps += sv[i]; }
      ps += __shfl_xor(ps, 16);
      ps += __shfl_xor(ps, 32);
      l[qt] = l[qt] * c + ps;
#pragma unroll
      for (int dt = 0; dt < 2; dt++) {
        Ot[dt][qt][0] *= c; Ot[dt][qt][1] *= c;
        Ot[dt][qt][2] *= c; Ot[dt][qt][3] *= c;
      }
#pragma unroll
      for (int kt = 0; kt < 2; kt++) {
        half4 p4;
        p4[0] = (_Float16)sv[kt * 4 + 0]; p4[1] = (_Float16)sv[kt * 4 + 1];
        p4[2] = (_Float16)sv[kt * 4 + 2]; p4[3] = (_Float16)sv[kt * 4 + 3];
        pB[qt][kt] = p4;
      }
    }

#pragma unroll
    for (int qt = 0; qt < 4; qt++)
#pragma unroll
      for (int dt = 0; dt < 2; dt++)
#pragma unroll
        for (int kt = 0; kt < 2; kt++)
          Ot[dt][qt] = __builtin_amdgcn_mfma_f32_16x16x16f16(
              vA[dt][kt], pB[qt][kt], Ot[dt][qt], 0, 0, 0);
  }

#pragma unroll
  for (int qt = 0; qt < 4; qt++) {
    float inv = 1.0f / l[qt];
#pragma unroll
    for (int dt = 0; dt < 2; dt++) {
      float4 ov;
      ov.x = Ot[dt][qt][0] * inv;
      ov.y = Ot[dt][qt][1] * inv;
      ov.z = Ot[dt][qt][2] * inv;
      ov.w = Ot[dt][qt][3] * inv;
      *(float4*)(qo + qptr[qt] + dt * 16 + quad * 4) = ov;
    }
  }
}

// ============================ launch ======================================
extern "C" void kernel_launch(void* const* d_in, const int* in_sizes, int n_in,
                              void* d_out, int out_size, void* d_ws, size_t ws_size,
                              hipStream_t stream) {
  const float* x_wsa      = (const float*)d_in[0];
  const float* x_orig     = (const float*)d_in[1];
  const float* q_w        = (const float*)d_in[2];
  const float* q_b        = (const float*)d_in[3];
  const float* kv_w       = (const float*)d_in[4];
  const float* kv_b       = (const float*)d_in[5];
  const float* out_w      = (const float*)d_in[6];
  const float* out_b      = (const float*)d_in[7];
  const float* bias_table = (const float*)d_in[8];
  const float* rezero     = (const float*)d_in[9];
  float* out = (float*)d_out;

  float*     qo    = (float*)d_ws;                               // 64 MB (q, then o in-place)
  _Float16*  kvbuf = (_Float16*)((char*)d_ws + 67108864);        // 64 MB f16
  _Float16*  wTbuf = (_Float16*)((char*)d_ws + 134217728);       // 0.8 MB f16

  const int M = 4 * IMG * IMG;  // 65536

  wt_kernel<<<25, 512, 0, stream>>>(kv_w, wTbuf);

  gemm_bias_kernel<<<dim3(M / BM, CDIM / BN), 256, 0, stream>>>(
      x_wsa, q_w, q_b, nullptr, qo, M, CDIM, CDIM);

  conv_mfma_kernel<<<dim3(64, 8, 4), 256, 0, stream>>>(x_orig, wTbuf, kv_b, kvbuf);

  attn_mfma_kernel<<<dim3(256, 8), 256, 0, stream>>>(qo, kvbuf, bias_table);

  gemm_bias_kernel<<<dim3(M / BM, CDIM / BN), 256, 0, stream>>>(
      qo, out_w, out_b, rezero, out, M, CDIM, CDIM);
}

// Round 4
// 351.499 us; speedup vs baseline: 4.7636x; 1.4338x over previous
//
#include <hip/hip_runtime.h>
#include <math.h>

#define IMG 128
#define CDIM 256
#define NHEADS 8
#define DHEAD 32

typedef _Float16 half8 __attribute__((ext_vector_type(8)));
typedef _Float16 half4 __attribute__((ext_vector_type(4)));
typedef float floatx4 __attribute__((ext_vector_type(4)));

// ==================== one-time weight transposes (f32 -> f16) ==============
// w: [256][256] row-major (k rows, n cols) -> wT: [n][k] f16
__global__ __launch_bounds__(256) void transpose_w_kernel(
    const float* __restrict__ w, _Float16* __restrict__ wT)
{
  const int n = blockIdx.x;
  const int k = threadIdx.x;
  wT[(size_t)n * 256 + k] = (_Float16)w[(size_t)k * 256 + n];
}

// conv weights: (25*32, 512) f32 -> wT: (8, 25, 64, 32) f16
__global__ __launch_bounds__(512) void wt_kernel(const float* __restrict__ w,
                                                 _Float16* __restrict__ wT)
{
  const int tap = blockIdx.x;          // 0..24
  const int t = threadIdx.x;           // 0..511 = global oc
  const int g = t >> 6, o = t & 63;
  _Float16 h[32];
#pragma unroll
  for (int ic = 0; ic < 32; ic++)
    h[ic] = (_Float16)w[(size_t)(tap * 32 + ic) * 512 + t];
  half8* dst = (half8*)(wT + (((size_t)g * 25 + tap) * 64 + o) * 32);
#pragma unroll
  for (int i = 0; i < 4; i++) dst[i] = *(half8*)(h + i * 8);
}

// ==================== MFMA GEMM: C = scale*(A@B + bias) ====================
// A: M x 256 (fp32 or f16 per AF16), BT: [n][k] f16 (pre-transposed weights),
// C: M x 256 (f16 or fp32 per OUTF16). Block = 128x128 C-tile, 4 waves.
#define GSTR 40   // LDS row stride in f16 (32 data + 8 pad)

template <bool AF16, bool OUTF16>
__global__ __launch_bounds__(256) void gemm_mfma_kernel(
    const void* __restrict__ Ap, const _Float16* __restrict__ BT,
    const float* __restrict__ bias, const float* __restrict__ scale_ptr,
    void* __restrict__ Cp)
{
  __shared__ _Float16 As[128 * GSTR];   // 10240 B
  __shared__ _Float16 Bs[128 * GSTR];   // 10240 B

  const int tid = threadIdx.x;
  const int m0 = blockIdx.x * 128;
  const int n0 = blockIdx.y * 128;
  const int wave = tid >> 6, lane = tid & 63;
  const int lq = lane & 15, quad = lane >> 4;
  const int wm = (wave >> 1) * 64, wn = (wave & 1) * 64;

  floatx4 acc[4][4];
#pragma unroll
  for (int i = 0; i < 4; i++)
#pragma unroll
    for (int j = 0; j < 4; j++) acc[i][j] = (floatx4){0.f, 0.f, 0.f, 0.f};

  for (int kc = 0; kc < 8; kc++) {
    const int k0 = kc * 32;
    __syncthreads();
    if (AF16) {
      const _Float16* A = (const _Float16*)Ap;
#pragma unroll
      for (int r = 0; r < 2; r++) {
        int idx = tid + r * 256;               // 0..511
        int row = idx >> 2, c8 = (idx & 3) * 8;
        *(half8*)(As + row * GSTR + c8) =
            *(const half8*)(A + (size_t)(m0 + row) * 256 + k0 + c8);
      }
    } else {
      const float* A = (const float*)Ap;
#pragma unroll
      for (int r = 0; r < 4; r++) {
        int idx = tid + r * 256;               // 0..1023
        int row = idx >> 3, c4 = (idx & 7) * 4;
        float4 v = *(const float4*)(A + (size_t)(m0 + row) * 256 + k0 + c4);
        half4 h;
        h[0] = (_Float16)v.x; h[1] = (_Float16)v.y;
        h[2] = (_Float16)v.z; h[3] = (_Float16)v.w;
        *(half4*)(As + row * GSTR + c4) = h;
      }
    }
#pragma unroll
    for (int r = 0; r < 2; r++) {
      int idx = tid + r * 256;
      int row = idx >> 2, c8 = (idx & 3) * 8;
      *(half8*)(Bs + row * GSTR + c8) =
          *(const half8*)(BT + (size_t)(n0 + row) * 256 + k0 + c8);
    }
    __syncthreads();

    half8 aF[4], bF[4];
#pragma unroll
    for (int i = 0; i < 4; i++) {
      aF[i] = *(const half8*)(As + (wm + i * 16 + lq) * GSTR + quad * 8);
      bF[i] = *(const half8*)(Bs + (wn + i * 16 + lq) * GSTR + quad * 8);
    }
#pragma unroll
    for (int mt = 0; mt < 4; mt++)
#pragma unroll
      for (int nt = 0; nt < 4; nt++)
        acc[mt][nt] = __builtin_amdgcn_mfma_f32_16x16x32_f16(
            aF[mt], bF[nt], acc[mt][nt], 0, 0, 0);
  }

  const float s = scale_ptr ? scale_ptr[0] : 1.0f;
#pragma unroll
  for (int nt = 0; nt < 4; nt++) {
    const int n = n0 + wn + nt * 16 + lq;
    const float bv = bias[n];
#pragma unroll
    for (int mt = 0; mt < 4; mt++) {
      const int mbase = m0 + wm + mt * 16 + quad * 4;
#pragma unroll
      for (int r = 0; r < 4; r++) {
        float val = s * (acc[mt][nt][r] + bv);
        if (OUTF16)
          ((_Float16*)Cp)[(size_t)(mbase + r) * 256 + n] = (_Float16)val;
        else
          ((float*)Cp)[(size_t)(mbase + r) * 256 + n] = val;
      }
    }
  }
}

// ==================== grouped 5x5 conv via implicit-GEMM MFMA ==============
#define PS 40   // patch pixel stride in f16
#define PW 20

__global__ __launch_bounds__(256, 2) void conv_mfma_kernel(
    const float* __restrict__ xin, const _Float16* __restrict__ wT,
    const float* __restrict__ bias, _Float16* __restrict__ kvout)
{
  __shared__ _Float16 patch[400 * PS];    // 32000 B
  __shared__ _Float16 wsl[5 * 64 * 32];   // 20480 B

  const int tid  = threadIdx.x;
  const int tile = blockIdx.x;
  const int g    = blockIdx.y;
  const int b    = blockIdx.z;
  const int ty0 = (tile >> 3) * 16, tx0 = (tile & 7) * 16;

  for (int idx = tid; idx < 800; idx += 256) {
    int pix = idx >> 1, c0 = (idx & 1) * 16;
    int py = pix / 20, px = pix - py * 20;
    int gy = ty0 + py - 2, gx = tx0 + px - 2;
    _Float16 h[16];
    if ((unsigned)gy < (unsigned)IMG && (unsigned)gx < (unsigned)IMG) {
      const float4* src = (const float4*)(xin + ((((size_t)b * IMG + gy) * IMG) + gx) * CDIM + g * 32 + c0);
#pragma unroll
      for (int i = 0; i < 4; i++) {
        float4 v = src[i];
        h[i * 4 + 0] = (_Float16)v.x; h[i * 4 + 1] = (_Float16)v.y;
        h[i * 4 + 2] = (_Float16)v.z; h[i * 4 + 3] = (_Float16)v.w;
      }
    } else {
#pragma unroll
      for (int i = 0; i < 16; i++) h[i] = (_Float16)0.f;
    }
    *(half8*)(patch + pix * PS + c0)     = *(half8*)h;
    *(half8*)(patch + pix * PS + c0 + 8) = *(half8*)(h + 8);
  }

  const int wave = tid >> 6, lane = tid & 63;
  const int lq = lane & 15, quad = lane >> 4;

  floatx4 acc[4][4];
#pragma unroll
  for (int i = 0; i < 4; i++)
#pragma unroll
    for (int j = 0; j < 4; j++) acc[i][j] = (floatx4){0.f, 0.f, 0.f, 0.f};

  const _Float16* wg = wT + (size_t)g * 25 * 64 * 32;

  for (int ky = 0; ky < 5; ky++) {
    __syncthreads();
    {
      const half8* src = (const half8*)(wg + (size_t)ky * 5 * 64 * 32);
      half8* dst = (half8*)wsl;
      for (int i = tid; i < 1280; i += 256) dst[i] = src[i];
    }
    __syncthreads();
#pragma unroll
    for (int kx = 0; kx < 5; kx++) {
      half8 bfr[4];
#pragma unroll
      for (int nt = 0; nt < 4; nt++) {
        int py = wave * 4 + nt + ky;
        bfr[nt] = *(const half8*)(patch + (py * PW + lq + kx) * PS + quad * 8);
      }
#pragma unroll
      for (int mt = 0; mt < 4; mt++) {
        half8 afr = *(const half8*)(wsl + ((kx * 64) + mt * 16 + lq) * 32 + quad * 8);
#pragma unroll
        for (int nt = 0; nt < 4; nt++)
          acc[mt][nt] = __builtin_amdgcn_mfma_f32_16x16x32_f16(afr, bfr[nt], acc[mt][nt], 0, 0, 0);
      }
    }
  }

#pragma unroll
  for (int mt = 0; mt < 4; mt++) {
    float4 bv = *(const float4*)(bias + g * 64 + mt * 16 + quad * 4);
#pragma unroll
    for (int nt = 0; nt < 4; nt++) {
      int oy = ty0 + wave * 4 + nt;
      int ox = tx0 + lq;
      half4 ov;
      ov[0] = (_Float16)(acc[mt][nt][0] + bv.x);
      ov[1] = (_Float16)(acc[mt][nt][1] + bv.y);
      ov[2] = (_Float16)(acc[mt][nt][2] + bv.z);
      ov[3] = (_Float16)(acc[mt][nt][3] + bv.w);
      *(half4*)(kvout + ((((size_t)b * IMG + oy) * IMG) + ox) * 512 + g * 64 + mt * 16 + quad * 4) = ov;
    }
  }
}

// ====================== MFMA flash attention (S^T trick) ===================
#define KSTR 40    // K row stride in f16
#define VSTR 264   // Vt row stride in f16

__global__ __launch_bounds__(256, 3) void attn_mfma_kernel(
    _Float16* __restrict__ qf, const _Float16* __restrict__ kv,
    const float* __restrict__ bias_table)
{
  __shared__ _Float16 Kl[256 * KSTR];
  __shared__ _Float16 Vt[32 * VSTR];
  __shared__ float bsm[961];

  const int tid = threadIdx.x;
  const int n  = blockIdx.x;
  const int hh = blockIdx.y;
  const int b  = n >> 6;
  const int wy = (n >> 3) & 7;
  const int wx = n & 7;
  const int y0 = wy * 16, x0 = wx * 16;

  for (int i = tid; i < 961; i += 256) bsm[i] = bias_table[i * 8 + hh];

  {
    const int ty = tid >> 4, tx = tid & 15;
    size_t base = ((((size_t)b * IMG + y0 + ty) * IMG) + x0 + tx) * 512;
    const half8* kp = (const half8*)(kv + base + hh * 32);
    const half8* vp = (const half8*)(kv + base + 256 + hh * 32);
#pragma unroll
    for (int i = 0; i < 4; i++)
      *(half8*)(Kl + tid * KSTR + i * 8) = kp[i];
    half8 vh[4];
#pragma unroll
    for (int i = 0; i < 4; i++) vh[i] = vp[i];
#pragma unroll
    for (int i = 0; i < 4; i++)
#pragma unroll
      for (int j = 0; j < 8; j++)
        Vt[(i * 8 + j) * VSTR + tid] = vh[i][j];
  }

  const int wave = tid >> 6, lane = tid & 63;
  const int lq = lane & 15, quad = lane >> 4;

  half8 qB[4];
  int qbase[4];
  size_t qptr[4];
#pragma unroll
  for (int qt = 0; qt < 4; qt++) {
    int tok = wave * 64 + qt * 16 + lq;
    int qy = tok >> 4, qx = tok & 15;
    qbase[qt] = (qy + 15) * 31 + (qx + 15);
    size_t p = ((((size_t)b * IMG + y0 + qy) * IMG) + x0 + qx) * CDIM + hh * 32;
    qptr[qt] = p;
    qB[qt] = *(const half8*)(qf + p + quad * 8);
  }

  __syncthreads();

  float m[4] = {-1e30f, -1e30f, -1e30f, -1e30f};
  float l[4] = {0.f, 0.f, 0.f, 0.f};
  floatx4 Ot[2][4];
#pragma unroll
  for (int dt = 0; dt < 2; dt++)
#pragma unroll
    for (int qt = 0; qt < 4; qt++) Ot[dt][qt] = (floatx4){0.f, 0.f, 0.f, 0.f};

  const float scale = 0.17677669529663687f;

  for (int ch = 0; ch < 8; ch++) {
    half8 kA[2];
#pragma unroll
    for (int kt = 0; kt < 2; kt++)
      kA[kt] = *(const half8*)(Kl + (ch * 32 + kt * 16 + lq) * KSTR + quad * 8);

    floatx4 S[4][2];
#pragma unroll
    for (int qt = 0; qt < 4; qt++)
#pragma unroll
      for (int kt = 0; kt < 2; kt++)
        S[qt][kt] = __builtin_amdgcn_mfma_f32_16x16x32_f16(
            kA[kt], qB[qt], (floatx4){0.f, 0.f, 0.f, 0.f}, 0, 0, 0);

    half4 vA[2][2];
#pragma unroll
    for (int dt = 0; dt < 2; dt++)
#pragma unroll
      for (int kt = 0; kt < 2; kt++)
        vA[dt][kt] = *(const half4*)(Vt + (dt * 16 + lq) * VSTR +
                                     ch * 32 + kt * 16 + quad * 4);

    half4 pB[4][2];
#pragma unroll
    for (int qt = 0; qt < 4; qt++) {
      float sv[8];
#pragma unroll
      for (int kt = 0; kt < 2; kt++) {
        int keybase = ch * 32 + kt * 16 + quad * 4;
        int koff = (keybase >> 4) * 31 + (keybase & 15);
#pragma unroll
        for (int r = 0; r < 4; r++)
          sv[kt * 4 + r] = S[qt][kt][r] * scale + bsm[qbase[qt] - koff - r];
      }
      float mx = sv[0];
#pragma unroll
      for (int i = 1; i < 8; i++) mx = fmaxf(mx, sv[i]);
      mx = fmaxf(mx, __shfl_xor(mx, 16));
      mx = fmaxf(mx, __shfl_xor(mx, 32));
      float mn = fmaxf(m[qt], mx);
      float c = __expf(m[qt] - mn);
      m[qt] = mn;
      float ps = 0.f;
#pragma unroll
      for (int i = 0; i < 8; i++) { sv[i] = __expf(sv[i] - mn); ps += sv[i]; }
      ps += __shfl_xor(ps, 16);
      ps += __shfl_xor(ps, 32);
      l[qt] = l[qt] * c + ps;
#pragma unroll
      for (int dt = 0; dt < 2; dt++) {
        Ot[dt][qt][0] *= c; Ot[dt][qt][1] *= c;
        Ot[dt][qt][2] *= c; Ot[dt][qt][3] *= c;
      }
#pragma unroll
      for (int kt = 0; kt < 2; kt++) {
        half4 p4;
        p4[0] = (_Float16)sv[kt * 4 + 0]; p4[1] = (_Float16)sv[kt * 4 + 1];
        p4[2] = (_Float16)sv[kt * 4 + 2]; p4[3] = (_Float16)sv[kt * 4 + 3];
        pB[qt][kt] = p4;
      }
    }

#pragma unroll
    for (int qt = 0; qt < 4; qt++)
#pragma unroll
      for (int dt = 0; dt < 2; dt++)
#pragma unroll
        for (int kt = 0; kt < 2; kt++)
          Ot[dt][qt] = __builtin_amdgcn_mfma_f32_16x16x16f16(
              vA[dt][kt], pB[qt][kt], Ot[dt][qt], 0, 0, 0);
  }

#pragma unroll
  for (int qt = 0; qt < 4; qt++) {
    float inv = 1.0f / l[qt];
#pragma unroll
    for (int dt = 0; dt < 2; dt++) {
      half4 ov;
      ov[0] = (_Float16)(Ot[dt][qt][0] * inv);
      ov[1] = (_Float16)(Ot[dt][qt][1] * inv);
      ov[2] = (_Float16)(Ot[dt][qt][2] * inv);
      ov[3] = (_Float16)(Ot[dt][qt][3] * inv);
      *(half4*)(qf + qptr[qt] + dt * 16 + quad * 4) = ov;
    }
  }
}

// ============================ launch ======================================
extern "C" void kernel_launch(void* const* d_in, const int* in_sizes, int n_in,
                              void* d_out, int out_size, void* d_ws, size_t ws_size,
                              hipStream_t stream) {
  const float* x_wsa      = (const float*)d_in[0];
  const float* x_orig     = (const float*)d_in[1];
  const float* q_w        = (const float*)d_in[2];
  const float* q_b        = (const float*)d_in[3];
  const float* kv_w       = (const float*)d_in[4];
  const float* kv_b       = (const float*)d_in[5];
  const float* out_w      = (const float*)d_in[6];
  const float* out_b      = (const float*)d_in[7];
  const float* bias_table = (const float*)d_in[8];
  const float* rezero     = (const float*)d_in[9];
  float* out = (float*)d_out;

  _Float16* qf    = (_Float16*)d_ws;                            // 32 MB (q, then o in-place)
  _Float16* kvbuf = (_Float16*)((char*)d_ws + 33554432);        // 64 MB
  _Float16* wTc   = (_Float16*)((char*)d_ws + 100663296);       // conv wT, 0.8 MB
  _Float16* qwT   = (_Float16*)((char*)d_ws + 101711872);       // 128 KB
  _Float16* owT   = (_Float16*)((char*)d_ws + 101974016);       // 128 KB

  transpose_w_kernel<<<256, 256, 0, stream>>>(q_w, qwT);
  transpose_w_kernel<<<256, 256, 0, stream>>>(out_w, owT);
  wt_kernel<<<25, 512, 0, stream>>>(kv_w, wTc);

  gemm_mfma_kernel<false, true><<<dim3(512, 2), 256, 0, stream>>>(
      x_wsa, qwT, q_b, nullptr, qf);

  conv_mfma_kernel<<<dim3(64, 8, 4), 256, 0, stream>>>(x_orig, wTc, kv_b, kvbuf);

  attn_mfma_kernel<<<dim3(256, 8), 256, 0, stream>>>(qf, kvbuf, bias_table);

  gemm_mfma_kernel<true, false><<<dim3(512, 2), 256, 0, stream>>>(
      qf, owT, out_b, rezero, out);
}